// Round 18
// baseline (351.352 us; speedup 1.0000x reference)
//
#include <hip/hip_runtime.h>

#define N_NODES 50000
#define N_EDGES 800000
#define BN_EPS 1e-5f

typedef unsigned int   u32;
typedef unsigned short u16;

__device__ __forceinline__ void fma4(float4& a, float s, const float4& w) {
    a.x += s * w.x; a.y += s * w.y; a.z += s * w.z; a.w += s * w.w;
}
__device__ __forceinline__ void add4(float4& a, const float4& b) {
    a.x += b.x; a.y += b.y; a.z += b.z; a.w += b.w;
}
// bf16 (RNE) pack/unpack
__device__ __forceinline__ u16 f2bf(float f) {
    union { u32 i; float f; } c; c.f = f;
    return (u16)((c.i + 0x7FFFu + ((c.i >> 16) & 1u)) >> 16);
}
__device__ __forceinline__ float4 bf4(uint2 w) {
    union { u32 i; float f; } a, b, c, d;
    a.i = w.x << 16; b.i = w.x & 0xFFFF0000u;
    c.i = w.y << 16; d.i = w.y & 0xFFFF0000u;
    return make_float4(a.f, b.f, c.f, d.f);
}
__device__ __forceinline__ uint2 pack4(const float4& v) {
    uint2 w;
    w.x = (u32)f2bf(v.x) | ((u32)f2bf(v.y) << 16);
    w.y = (u32)f2bf(v.z) | ((u32)f2bf(v.w) << 16);
    return w;
}
// extract element kk (compile-time) of 8 bf16 packed in a uint4
__device__ __forceinline__ float bfx(const uint4& v, int kk) {
    u32 w = ((const u32*)&v)[kk >> 1];
    union { u32 i; float f; } c;
    c.i = (kk & 1) ? (w & 0xFFFF0000u) : (w << 16);
    return c.f;
}

// XCD-aware 1-D grid decode (round-robin xcd = bid % 8).
template <int NY>
__device__ __forceinline__ bool xcd_decode(int nx, int& x, int& y) {
    const int s = blockIdx.x & (8 * NY - 1);
    const int g = blockIdx.x / (8 * NY);
    x = g * 8 + (s & 7);
    y = s >> 3;
    return x < nx;
}
static inline int xcd_grid(int nx, int ny) { return ((nx + 7) / 8 * 8) * ny; }

// ---------------------------------------------------------------------------
__global__ void zero_i(int* __restrict__ p, int n) {
    int i = blockIdx.x * blockDim.x + threadIdx.x;
    int stride = gridDim.x * blockDim.x;
    for (; i < n; i += stride) p[i] = 0;
}

// ---------------------------------------------------------------------------
// CSR build
__global__ void hist_kernel(const int* __restrict__ dst, int* __restrict__ cnt) {
    int i = blockIdx.x * blockDim.x + threadIdx.x;
    int stride = gridDim.x * blockDim.x;
    for (; i < N_EDGES; i += stride) atomicAdd(&cnt[dst[i]], 1);
}
__global__ void scan1_kernel(const int* __restrict__ cnt, int* __restrict__ rp,
                             int* __restrict__ bsum) {
    __shared__ int s[256];
    int t = threadIdx.x;
    int idx = blockIdx.x * 256 + t;
    int v = (idx < N_NODES) ? cnt[idx] : 0;
    s[t] = v;
    __syncthreads();
    for (int off = 1; off < 256; off <<= 1) {
        int x = 0;
        if (t >= off) x = s[t - off];
        __syncthreads();
        s[t] += x;
        __syncthreads();
    }
    if (idx < N_NODES) rp[idx] = s[t] - v;
    if (t == 255) bsum[blockIdx.x] = s[255];
}
__global__ void scan2_kernel(int* __restrict__ bsum, int nb, float* __restrict__ stats) {
    __shared__ int s[256];
    int t = threadIdx.x;
    for (int i = t; i < 5 * 256; i += 256) stats[i] = 0.f;
    int v = (t < nb) ? bsum[t] : 0;
    s[t] = v;
    __syncthreads();
    for (int off = 1; off < 256; off <<= 1) {
        int x = 0;
        if (t >= off) x = s[t - off];
        __syncthreads();
        s[t] += x;
        __syncthreads();
    }
    if (t < nb) bsum[t] = s[t] - v;
}
__global__ void scan3_kernel(int* __restrict__ rp, const int* __restrict__ bsum,
                             int* __restrict__ cnt) {
    int idx = blockIdx.x * 256 + threadIdx.x;
    if (idx < N_NODES) {
        rp[idx] += bsum[blockIdx.x];
        cnt[idx] = 0;
    }
    if (idx == 0) rp[N_NODES] = N_EDGES;
}
// after fill completes, cnt[n] == degree(n) again.
__global__ void fill_kernel(const int* __restrict__ src, const int* __restrict__ dst,
                            const int* __restrict__ rp, int* __restrict__ cur,
                            u16* __restrict__ ssrc) {
    int i = blockIdx.x * blockDim.x + threadIdx.x;
    int stride = gridDim.x * blockDim.x;
    for (; i < N_EDGES; i += stride) {
        int d = dst[i];
        int p = rp[d] + atomicAdd(&cur[d], 1);
        ssrc[p] = (u16)src[i];
    }
}

// ---------------------------------------------------------------------------
// embedding Linear(5,32)+ReLU with fused BN stats; bf16 output.
__global__ __launch_bounds__(256) void emb_fused(
    const float* __restrict__ x, const float* __restrict__ W,
    const float* __restrict__ b, u16* __restrict__ out16,
    float* __restrict__ stats) {
    __shared__ float lsum[32], lssq[32];
    if (threadIdx.x < 32) { lsum[threadIdx.x] = 0.f; lssq[threadIdx.x] = 0.f; }
    __syncthreads();
    const int o = threadIdx.x & 31;
    const int total = N_NODES * 32;
    float mys = 0.f, myq = 0.f;
    for (int base = blockIdx.x * 256; base < total; base += gridDim.x * 256) {
        int idx = base + threadIdx.x;
        float acc = 0.f;
        if (idx < total) {
            int n = idx >> 5;
            const float* xr = x + n * 5;
            acc = b[o];
#pragma unroll
            for (int k = 0; k < 5; ++k) acc += xr[k] * W[k * 32 + o];
            acc = fmaxf(acc, 0.f);
            out16[idx] = f2bf(acc);
        }
        mys += acc;
        myq += acc * acc;
    }
    mys += __shfl_xor(mys, 32);
    myq += __shfl_xor(myq, 32);
    if ((threadIdx.x & 63) < 32) { atomicAdd(&lsum[o], mys); atomicAdd(&lssq[o], myq); }
    __syncthreads();
    if (threadIdx.x < 32) {
        atomicAdd(&stats[threadIdx.x], lsum[threadIdx.x]);
        atomicAdd(&stats[32 + threadIdx.x], lssq[threadIdx.x]);
    }
}

// ---------------------------------------------------------------------------
template <int D>
__device__ __forceinline__ void bn_finalize_lds(
    const float* __restrict__ stats, const float* __restrict__ g,
    const float* __restrict__ beta, float* sc, float* sh) {
    const float invN = 1.f / (float)N_NODES;
    for (int f = threadIdx.x; f < D; f += 256) {
        float m = stats[f] * invN;
        float var = stats[D + f] * invN - m * m;
        float a = g[f] * rsqrtf(var + BN_EPS);
        sc[f] = a;
        sh[f] = beta[f] - m * a;
    }
    __syncthreads();
}

// ---------------------------------------------------------------------------
// batchnorm + relu: read bf16 raw, write bf16 normalized mirror.
__global__ __launch_bounds__(256) void bn_apply16(
    const uint2* __restrict__ in16, u16* __restrict__ out16,
    const float* __restrict__ g, const float* __restrict__ beta,
    const float* __restrict__ stats, int logD) {
    const int D = 1 << logD;
    const int total4 = N_NODES << (logD - 2);
    const float invN = 1.f / (float)N_NODES;
    int idx = blockIdx.x * blockDim.x + threadIdx.x;
    int stride = gridDim.x * blockDim.x;
    for (; idx < total4; idx += stride) {
        int f = (idx & ((D >> 2) - 1)) << 2;
        float4 v = bf4(in16[idx]);
        float* vp = (float*)&v;
#pragma unroll
        for (int c = 0; c < 4; ++c) {
            float m = stats[f + c] * invN;
            float var = stats[D + f + c] * invN - m * m;
            vp[c] = fmaxf((vp[c] - m) * rsqrtf(var + BN_EPS) * g[f + c] + beta[f + c], 0.f);
        }
        ((uint2*)out16)[idx] = pack4(v);
    }
}

// ---------------------------------------------------------------------------
// agg16[n] = bf16( sum over CSR row of bf16 h16[ssrc[e]] )
template <int LOGD>
__global__ __launch_bounds__(256) void gather_agg_bf16(
    const u16* __restrict__ h16, const int* __restrict__ rp,
    const u16* __restrict__ ssrc, uint2* __restrict__ agg16) {
    constexpr int QSH = LOGD - 2;
    int tid = blockIdx.x * 256 + threadIdx.x;
    int node = tid >> QSH;
    if (node >= N_NODES) return;
    int q = tid & ((1 << QSH) - 1);
    int e0 = rp[node], e1 = rp[node + 1];
    float4 acc = make_float4(0.f, 0.f, 0.f, 0.f);
    int e = e0;
    for (; e + 4 <= e1; e += 4) {
        int s0 = ssrc[e], s1 = ssrc[e + 1], s2 = ssrc[e + 2], s3 = ssrc[e + 3];
        uint2 w0 = ((const uint2*)(h16 + ((size_t)s0 << LOGD)))[q];
        uint2 w1 = ((const uint2*)(h16 + ((size_t)s1 << LOGD)))[q];
        uint2 w2 = ((const uint2*)(h16 + ((size_t)s2 << LOGD)))[q];
        uint2 w3 = ((const uint2*)(h16 + ((size_t)s3 << LOGD)))[q];
        float4 v0 = bf4(w0), v1 = bf4(w1), v2 = bf4(w2), v3 = bf4(w3);
        add4(v0, v1); add4(v2, v3); add4(acc, v0); add4(acc, v2);
    }
    for (; e < e1; ++e) {
        float4 v = bf4(((const uint2*)(h16 + ((size_t)ssrc[e] << LOGD)))[q]);
        add4(acc, v);
    }
    agg16[tid] = pack4(acc);
}

// ---------------------------------------------------------------------------
// Layer-0 dual matmul, bf16 operands; BN folded per-node via linearity.
// Output bf16 raw. XCD-aware (NY=2).
template <int DIN, int DOUT, int OBL, int NPT>
__global__ __launch_bounds__(256) void gconv_bn0(
    const u16* __restrict__ h16, const u16* __restrict__ agg16,
    const float* __restrict__ Wrel, const float* __restrict__ brel,
    const float* __restrict__ Wroot, u16* __restrict__ out16,
    const float* __restrict__ stats_in, const float* __restrict__ g_in,
    const float* __restrict__ beta_in, const int* __restrict__ deg,
    float* __restrict__ stats_out, int nx) {
    constexpr int NY = 2;
    constexpr int LPN = OBL / 4;
    constexpr int SLOTS = 256 / LPN;
    constexpr int KS = 8;
    constexpr int TOT4 = DIN * OBL / 4;
    int bx, by;
    if (!xcd_decode<NY>(nx, bx, by)) return;
    __shared__ __align__(16) float wl[2 * DIN * OBL];
    __shared__ __align__(16) float sc[DIN];
    __shared__ __align__(16) float sh[DIN];
    __shared__ float lsum[OBL], lssq[OBL];
    const int ob0 = by * OBL;
    for (int e4 = threadIdx.x; e4 < TOT4; e4 += 256) {
        int k = e4 / (OBL / 4);
        int j = (e4 % (OBL / 4)) * 4;
        ((float4*)wl)[e4] = *(const float4*)(Wrel + (size_t)k * DOUT + ob0 + j);
        ((float4*)wl)[TOT4 + e4] = *(const float4*)(Wroot + (size_t)k * DOUT + ob0 + j);
    }
    if (threadIdx.x < OBL) { lsum[threadIdx.x] = 0.f; lssq[threadIdx.x] = 0.f; }
    bn_finalize_lds<DIN>(stats_in, g_in, beta_in, sc, sh);  // syncs

    const int q = threadIdx.x & (LPN - 1);
    const int slot = threadIdx.x / LPN;
    const int o0 = ob0 + q * 4;
    const int nbase = bx * (SLOTS * NPT) + slot;

    float degf[NPT];
#pragma unroll
    for (int i = 0; i < NPT; ++i) {
        int n = nbase + i * SLOTS;
        degf[i] = (n < N_NODES) ? (float)deg[n] : 0.f;
    }

    float4 bias = *(const float4*)(brel + o0);
    float4 acc[NPT];
#pragma unroll
    for (int i = 0; i < NPT; ++i) acc[i] = bias;

#pragma unroll 1
    for (int s = 0; s < DIN / KS; ++s) {
        const int k0 = s * KS;
        float4 s2[2] = {((const float4*)sc)[k0 / 4], ((const float4*)sc)[k0 / 4 + 1]};
        float4 t2[2] = {((const float4*)sh)[k0 / 4], ((const float4*)sh)[k0 / 4 + 1]};
        const float* scp = (const float*)s2;
        const float* shp = (const float*)t2;
        uint4 hv16[NPT], av16[NPT];
#pragma unroll
        for (int i = 0; i < NPT; ++i) {
            int n = nbase + i * SLOTS;
            int nn = (n < N_NODES) ? n : 0;
            hv16[i] = *(const uint4*)(h16 + (size_t)nn * DIN + k0);
            av16[i] = *(const uint4*)(agg16 + (size_t)nn * DIN + k0);
        }
#pragma unroll
        for (int kk = 0; kk < KS; ++kk) {
            float4 wr = *(const float4*)&wl[(k0 + kk) * OBL + q * 4];
            float4 wo = *(const float4*)&wl[DIN * OBL + (k0 + kk) * OBL + q * 4];
#pragma unroll
            for (int i = 0; i < NPT; ++i) {
                float a  = fmaf(bfx(av16[i], kk), scp[kk], degf[i] * shp[kk]);
                float hh = fmaf(bfx(hv16[i], kk), scp[kk], shp[kk]);
                fma4(acc[i], a, wr);
                fma4(acc[i], hh, wo);
            }
        }
    }
#pragma unroll
    for (int i = 0; i < NPT; ++i) {
        int n = nbase + i * SLOTS;
        if (n < N_NODES)
            *(uint2*)(out16 + (size_t)n * DOUT + o0) = pack4(acc[i]);
        else
            acc[i] = make_float4(0.f, 0.f, 0.f, 0.f);
    }
    float4 s4 = make_float4(0.f, 0.f, 0.f, 0.f);
    float4 q4 = make_float4(0.f, 0.f, 0.f, 0.f);
#pragma unroll
    for (int i = 0; i < NPT; ++i) {
        s4.x += acc[i].x; s4.y += acc[i].y; s4.z += acc[i].z; s4.w += acc[i].w;
        q4.x += acc[i].x * acc[i].x; q4.y += acc[i].y * acc[i].y;
        q4.z += acc[i].z * acc[i].z; q4.w += acc[i].w * acc[i].w;
    }
#pragma unroll
    for (int d = LPN; d < 64; d <<= 1) {
        s4.x += __shfl_xor(s4.x, d); s4.y += __shfl_xor(s4.y, d);
        s4.z += __shfl_xor(s4.z, d); s4.w += __shfl_xor(s4.w, d);
        q4.x += __shfl_xor(q4.x, d); q4.y += __shfl_xor(q4.y, d);
        q4.z += __shfl_xor(q4.z, d); q4.w += __shfl_xor(q4.w, d);
    }
    if ((threadIdx.x & 63) < LPN) {
        int c = q * 4;
        atomicAdd(&lsum[c + 0], s4.x); atomicAdd(&lsum[c + 1], s4.y);
        atomicAdd(&lsum[c + 2], s4.z); atomicAdd(&lsum[c + 3], s4.w);
        atomicAdd(&lssq[c + 0], q4.x); atomicAdd(&lssq[c + 1], q4.y);
        atomicAdd(&lssq[c + 2], q4.z); atomicAdd(&lssq[c + 3], q4.w);
    }
    __syncthreads();
    if (threadIdx.x < OBL) {
        atomicAdd(&stats_out[ob0 + threadIdx.x], lsum[threadIdx.x]);
        atomicAdd(&stats_out[DOUT + ob0 + threadIdx.x], lssq[threadIdx.x]);
    }
}

// ---------------------------------------------------------------------------
// dual matmul, bf16 operands -> bf16 raw output + stats; XCD-aware (NY=4).
template <int DIN, int DOUT, int OBL, int NPT>
__global__ __launch_bounds__(256) void gconv_lds(
    const u16* __restrict__ h16, const u16* __restrict__ agg16,
    const float* __restrict__ Wrel, const float* __restrict__ brel,
    const float* __restrict__ Wroot, u16* __restrict__ out16,
    float* __restrict__ stats_out, int nx) {
    constexpr int NY = DOUT / OBL;
    constexpr int LPN = OBL / 4;
    constexpr int SLOTS = 256 / LPN;
    constexpr int KS = 8;
    constexpr int TOT4 = DIN * OBL / 4;
    int bx, by;
    if (!xcd_decode<NY>(nx, bx, by)) return;
    __shared__ __align__(16) float wl[2 * DIN * OBL];
    __shared__ float lsum[OBL], lssq[OBL];
    const int ob0 = by * OBL;
    for (int e4 = threadIdx.x; e4 < TOT4; e4 += 256) {
        int k = e4 / (OBL / 4);
        int j = (e4 % (OBL / 4)) * 4;
        ((float4*)wl)[e4] = *(const float4*)(Wrel + (size_t)k * DOUT + ob0 + j);
        ((float4*)wl)[TOT4 + e4] = *(const float4*)(Wroot + (size_t)k * DOUT + ob0 + j);
    }
    if (threadIdx.x < OBL) { lsum[threadIdx.x] = 0.f; lssq[threadIdx.x] = 0.f; }
    __syncthreads();

    const int q = threadIdx.x & (LPN - 1);
    const int slot = threadIdx.x / LPN;
    const int o0 = ob0 + q * 4;
    const int nbase = bx * (SLOTS * NPT) + slot;

    float4 bias = *(const float4*)(brel + o0);
    float4 acc[NPT];
#pragma unroll
    for (int i = 0; i < NPT; ++i) acc[i] = bias;

#pragma unroll 1
    for (int s = 0; s < DIN / KS; ++s) {
        const int k0 = s * KS;
        uint4 hv16[NPT], av16[NPT];
#pragma unroll
        for (int i = 0; i < NPT; ++i) {
            int n = nbase + i * SLOTS;
            int nn = (n < N_NODES) ? n : 0;
            hv16[i] = *(const uint4*)(h16 + (size_t)nn * DIN + k0);
            av16[i] = *(const uint4*)(agg16 + (size_t)nn * DIN + k0);
        }
#pragma unroll
        for (int kk = 0; kk < KS; ++kk) {
            float4 wr = *(const float4*)&wl[(k0 + kk) * OBL + q * 4];
            float4 wo = *(const float4*)&wl[DIN * OBL + (k0 + kk) * OBL + q * 4];
#pragma unroll
            for (int i = 0; i < NPT; ++i) {
                fma4(acc[i], bfx(av16[i], kk), wr);
                fma4(acc[i], bfx(hv16[i], kk), wo);
            }
        }
    }
#pragma unroll
    for (int i = 0; i < NPT; ++i) {
        int n = nbase + i * SLOTS;
        if (n < N_NODES)
            *(uint2*)(out16 + (size_t)n * DOUT + o0) = pack4(acc[i]);
        else
            acc[i] = make_float4(0.f, 0.f, 0.f, 0.f);
    }
    float4 s4 = make_float4(0.f, 0.f, 0.f, 0.f);
    float4 q4 = make_float4(0.f, 0.f, 0.f, 0.f);
#pragma unroll
    for (int i = 0; i < NPT; ++i) {
        s4.x += acc[i].x; s4.y += acc[i].y; s4.z += acc[i].z; s4.w += acc[i].w;
        q4.x += acc[i].x * acc[i].x; q4.y += acc[i].y * acc[i].y;
        q4.z += acc[i].z * acc[i].z; q4.w += acc[i].w * acc[i].w;
    }
#pragma unroll
    for (int d = LPN; d < 64; d <<= 1) {
        s4.x += __shfl_xor(s4.x, d); s4.y += __shfl_xor(s4.y, d);
        s4.z += __shfl_xor(s4.z, d); s4.w += __shfl_xor(s4.w, d);
        q4.x += __shfl_xor(q4.x, d); q4.y += __shfl_xor(q4.y, d);
        q4.z += __shfl_xor(q4.z, d); q4.w += __shfl_xor(q4.w, d);
    }
    if ((threadIdx.x & 63) < LPN) {
        int c = q * 4;
        atomicAdd(&lsum[c + 0], s4.x); atomicAdd(&lsum[c + 1], s4.y);
        atomicAdd(&lsum[c + 2], s4.z); atomicAdd(&lsum[c + 3], s4.w);
        atomicAdd(&lssq[c + 0], q4.x); atomicAdd(&lssq[c + 1], q4.y);
        atomicAdd(&lssq[c + 2], q4.z); atomicAdd(&lssq[c + 3], q4.w);
    }
    __syncthreads();
    if (threadIdx.x < OBL) {
        atomicAdd(&stats_out[ob0 + threadIdx.x], lsum[threadIdx.x]);
        atomicAdd(&stats_out[DOUT + ob0 + threadIdx.x], lssq[threadIdx.x]);
    }
}

// ---------------------------------------------------------------------------
// P(bf16) = bnrelu(h16)@Wrel ; Q(fp32) = bnrelu(h16)@Wroot + brel
// bf16 raw input, BN+ReLU folded per-node; XCD-aware (NY = DOUT/OBL).
template <int DIN, int DOUT, int OBL, int NPT>
__global__ __launch_bounds__(256) void prem_bn16(
    const u16* __restrict__ h16, const float* __restrict__ Wrel,
    const float* __restrict__ brel, const float* __restrict__ Wroot,
    u16* __restrict__ P16, float* __restrict__ Q,
    const float* __restrict__ stats_in, const float* __restrict__ g_in,
    const float* __restrict__ beta_in, int nx) {
    constexpr int NY = DOUT / OBL;
    constexpr int LPN = OBL / 4;
    constexpr int SLOTS = 256 / LPN;
    constexpr int KS = 8;
    constexpr int TOT4 = DIN * OBL / 4;
    int bx, by;
    if (!xcd_decode<NY>(nx, bx, by)) return;
    __shared__ __align__(16) float wl[2 * DIN * OBL];
    __shared__ __align__(16) float sc[DIN];
    __shared__ __align__(16) float sh[DIN];
    const int ob0 = by * OBL;
    for (int e4 = threadIdx.x; e4 < TOT4; e4 += 256) {
        int k = e4 / (OBL / 4);
        int j = (e4 % (OBL / 4)) * 4;
        ((float4*)wl)[e4] = *(const float4*)(Wrel + (size_t)k * DOUT + ob0 + j);
        ((float4*)wl)[TOT4 + e4] = *(const float4*)(Wroot + (size_t)k * DOUT + ob0 + j);
    }
    bn_finalize_lds<DIN>(stats_in, g_in, beta_in, sc, sh);  // syncs

    const int q = threadIdx.x & (LPN - 1);
    const int slot = threadIdx.x / LPN;
    const int o0 = ob0 + q * 4;
    const int nbase = bx * (SLOTS * NPT) + slot;

    float4 bias = *(const float4*)(brel + o0);
    float4 accp[NPT], accq[NPT];
#pragma unroll
    for (int i = 0; i < NPT; ++i) {
        accp[i] = make_float4(0.f, 0.f, 0.f, 0.f);
        accq[i] = bias;
    }

#pragma unroll 1
    for (int s = 0; s < DIN / KS; ++s) {
        const int k0 = s * KS;
        float4 s2[2] = {((const float4*)sc)[k0 / 4], ((const float4*)sc)[k0 / 4 + 1]};
        float4 t2[2] = {((const float4*)sh)[k0 / 4], ((const float4*)sh)[k0 / 4 + 1]};
        const float* scp = (const float*)s2;
        const float* shp = (const float*)t2;
        uint4 hv16[NPT];
#pragma unroll
        for (int i = 0; i < NPT; ++i) {
            int n = nbase + i * SLOTS;
            int nn = (n < N_NODES) ? n : 0;
            hv16[i] = *(const uint4*)(h16 + (size_t)nn * DIN + k0);
        }
#pragma unroll
        for (int kk = 0; kk < KS; ++kk) {
            float4 wr = *(const float4*)&wl[(k0 + kk) * OBL + q * 4];
            float4 wo = *(const float4*)&wl[DIN * OBL + (k0 + kk) * OBL + q * 4];
#pragma unroll
            for (int i = 0; i < NPT; ++i) {
                float hh = fmaxf(fmaf(bfx(hv16[i], kk), scp[kk], shp[kk]), 0.f);
                fma4(accp[i], hh, wr);
                fma4(accq[i], hh, wo);
            }
        }
    }
#pragma unroll
    for (int i = 0; i < NPT; ++i) {
        int n = nbase + i * SLOTS;
        if (n < N_NODES) {
            *(uint2*)(P16 + (size_t)n * DOUT + o0) = pack4(accp[i]);
            *(float4*)(Q + (size_t)n * DOUT + o0) = accq[i];
        }
    }
}

// ---------------------------------------------------------------------------
// out = Q_preloaded + sum over CSR row of bf16 P16[ssrc[e]]; fused BN stats.
template <int LOGD, int W16>
__global__ __launch_bounds__(256) void gather_add_bf16(
    const u16* __restrict__ P16, const int* __restrict__ rp,
    const u16* __restrict__ ssrc, float4* __restrict__ qio,
    u16* __restrict__ out16, float* __restrict__ stats) {
    constexpr int D = 1 << LOGD;
    constexpr int Q4 = D / 4;
    __shared__ float lsum[D], lssq[D];
    if (threadIdx.x < D) { lsum[threadIdx.x] = 0.f; lssq[threadIdx.x] = 0.f; }
    __syncthreads();

    const int total = N_NODES * Q4;
    const int q = threadIdx.x & (Q4 - 1);
    float4 mys = make_float4(0.f, 0.f, 0.f, 0.f);
    float4 myq = make_float4(0.f, 0.f, 0.f, 0.f);

    for (int base = blockIdx.x * 256; base < total; base += gridDim.x * 256) {
        int tid = base + threadIdx.x;
        float4 acc = make_float4(0.f, 0.f, 0.f, 0.f);
        if (tid < total) {
            int node = tid >> (LOGD - 2);
            int e0 = rp[node], e1 = rp[node + 1];
            acc = qio[tid];
            int e = e0;
            for (; e + 4 <= e1; e += 4) {
                int s0 = ssrc[e], s1 = ssrc[e + 1], s2 = ssrc[e + 2], s3 = ssrc[e + 3];
                uint2 w0 = ((const uint2*)(P16 + ((size_t)s0 << LOGD)))[q];
                uint2 w1 = ((const uint2*)(P16 + ((size_t)s1 << LOGD)))[q];
                uint2 w2 = ((const uint2*)(P16 + ((size_t)s2 << LOGD)))[q];
                uint2 w3 = ((const uint2*)(P16 + ((size_t)s3 << LOGD)))[q];
                float4 v0 = bf4(w0), v1 = bf4(w1), v2 = bf4(w2), v3 = bf4(w3);
                add4(v0, v1); add4(v2, v3); add4(acc, v0); add4(acc, v2);
            }
            for (; e < e1; ++e) {
                float4 v = bf4(((const uint2*)(P16 + ((size_t)ssrc[e] << LOGD)))[q]);
                add4(acc, v);
            }
            if (W16)
                ((uint2*)out16)[tid] = pack4(acc);
            else
                qio[tid] = acc;
        }
        mys.x += acc.x; mys.y += acc.y; mys.z += acc.z; mys.w += acc.w;
        myq.x += acc.x * acc.x; myq.y += acc.y * acc.y;
        myq.z += acc.z * acc.z; myq.w += acc.w * acc.w;
    }
#pragma unroll
    for (int d = Q4; d < 64; d <<= 1) {
        mys.x += __shfl_xor(mys.x, d); mys.y += __shfl_xor(mys.y, d);
        mys.z += __shfl_xor(mys.z, d); mys.w += __shfl_xor(mys.w, d);
        myq.x += __shfl_xor(myq.x, d); myq.y += __shfl_xor(myq.y, d);
        myq.z += __shfl_xor(myq.z, d); myq.w += __shfl_xor(myq.w, d);
    }
    if ((threadIdx.x & 63) < Q4) {
        atomicAdd(&lsum[4 * q + 0], mys.x); atomicAdd(&lsum[4 * q + 1], mys.y);
        atomicAdd(&lsum[4 * q + 2], mys.z); atomicAdd(&lsum[4 * q + 3], mys.w);
        atomicAdd(&lssq[4 * q + 0], myq.x); atomicAdd(&lssq[4 * q + 1], myq.y);
        atomicAdd(&lssq[4 * q + 2], myq.z); atomicAdd(&lssq[4 * q + 3], myq.w);
    }
    __syncthreads();
    if (threadIdx.x < D) {
        atomicAdd(&stats[threadIdx.x], lsum[threadIdx.x]);
        atomicAdd(&stats[D + threadIdx.x], lssq[threadIdx.x]);
    }
}

// ---------------------------------------------------------------------------
// fused: BN(layer3)+ReLU -> Linear(32,16)+ReLU -> Linear(16,2)
__global__ __launch_bounds__(256) void outmlp_kernel(
    const float* __restrict__ h, const float* __restrict__ stats,
    const float* __restrict__ g, const float* __restrict__ beta,
    const float* __restrict__ W1, const float* __restrict__ b1,
    const float* __restrict__ W2, const float* __restrict__ b2,
    float* __restrict__ out) {
    int n = blockIdx.x * 256 + threadIdx.x;
    if (n >= N_NODES) return;
    const float invN = 1.f / (float)N_NODES;
    const float4* hr4 = (const float4*)(h + (size_t)n * 32);
    float hv[32];
#pragma unroll
    for (int k4 = 0; k4 < 8; ++k4) {
        float4 v = hr4[k4];
        float* vp = (float*)&v;
#pragma unroll
        for (int c = 0; c < 4; ++c) {
            int f = 4 * k4 + c;
            float m = stats[f] * invN;
            float var = stats[32 + f] * invN - m * m;
            hv[f] = fmaxf((vp[c] - m) * rsqrtf(var + BN_EPS) * g[f] + beta[f], 0.f);
        }
    }
    float hid[16];
#pragma unroll
    for (int j = 0; j < 16; ++j) hid[j] = b1[j];
#pragma unroll
    for (int k = 0; k < 32; ++k) {
        float hk = hv[k];
#pragma unroll
        for (int j = 0; j < 16; ++j) hid[j] += hk * W1[k * 16 + j];
    }
    float o0 = b2[0], o1 = b2[1];
#pragma unroll
    for (int j = 0; j < 16; ++j) {
        float t = fmaxf(hid[j], 0.f);
        o0 += t * W2[j * 2 + 0];
        o1 += t * W2[j * 2 + 1];
    }
    out[n * 2 + 0] = o0;
    out[n * 2 + 1] = o1;
}

// ---------------------------------------------------------------------------
extern "C" void kernel_launch(void* const* d_in, const int* in_sizes, int n_in,
                              void* d_out, int out_size, void* d_ws, size_t ws_size,
                              hipStream_t stream) {
    const float* x        = (const float*)d_in[0];
    const int*   ei       = (const int*)d_in[1];
    const int*   src      = ei;
    const int*   dst      = ei + N_EDGES;
    const float* emb_W    = (const float*)d_in[2];
    const float* emb_b    = (const float*)d_in[3];
    const float* emb_g    = (const float*)d_in[4];
    const float* emb_beta = (const float*)d_in[5];
    const float* out_W1   = (const float*)d_in[26];
    const float* out_b1   = (const float*)d_in[27];
    const float* out_W2   = (const float*)d_in[28];
    const float* out_b2   = (const float*)d_in[29];

    float* ws = (float*)d_ws;
    // fp32 regions
    float* q32   = ws;                                   // N x 64 fp32 (Q panels; final h)
    float* stats = ws + (size_t)N_NODES * 64;            // 5 x 256
    // bf16 regions (u16 counts)
    u16* h16emb = (u16*)(stats + 5 * 256);               // N x 32
    u16* AGG16  = h16emb + (size_t)N_NODES * 32;         // N x 64 (agg / P panels)
    u16* r0_16  = AGG16 + (size_t)N_NODES * 64;          // N x 64 raw L0 out
    u16* h16a   = r0_16 + (size_t)N_NODES * 64;          // N x 64 normalized L0
    u16* r1_16  = h16a + (size_t)N_NODES * 64;           // N x 128 raw L1 out
    u16* h2_16  = r1_16 + (size_t)N_NODES * 128;         // N x 64 raw L2 out
    int* rp     = (int*)(h2_16 + (size_t)N_NODES * 64);  // 50001
    int* cnt    = rp + N_NODES + 1;
    int* bsum   = cnt + N_NODES;
    u16* ssrc   = (u16*)(bsum + 256);                    // 800000

    float* st0 = stats;        // emb BN (D=32)
    float* st1 = stats + 256;  // L0 (D=64)
    float* st2 = stats + 512;  // L1 (D=128)
    float* st3 = stats + 768;  // L2 (D=64)
    float* st4 = stats + 1024; // L3 (D=32)

    const int BS = 256;
    const int NB = (N_NODES + BS - 1) / BS;  // 196

    // ---- CSR build ----
    zero_i<<<64, BS, 0, stream>>>(cnt, N_NODES);
    hist_kernel<<<1024, BS, 0, stream>>>(dst, cnt);
    scan1_kernel<<<NB, 256, 0, stream>>>(cnt, rp, bsum);
    scan2_kernel<<<1, 256, 0, stream>>>(bsum, NB, stats);
    scan3_kernel<<<NB, 256, 0, stream>>>(rp, bsum, cnt);
    fill_kernel<<<1024, BS, 0, stream>>>(src, dst, rp, cnt, ssrc);
    // after fill: cnt[n] == degree(n)

    // ---- embedding ----
    emb_fused<<<512, BS, 0, stream>>>(x, emb_W, emb_b, h16emb, st0);

    // ---- layer 0: 32 -> 64  (NPT=2) ----
    gather_agg_bf16<5><<<(N_NODES * 8 + BS - 1) / BS, BS, 0, stream>>>(h16emb, rp, ssrc, (uint2*)AGG16);
    {
        const int nx = (N_NODES + 63) / 64;  // 782
        gconv_bn0<32, 64, 32, 2><<<xcd_grid(nx, 2), BS, 0, stream>>>(
            h16emb, AGG16, (const float*)d_in[6], (const float*)d_in[7], (const float*)d_in[8],
            r0_16, st0, emb_g, emb_beta, cnt, st1, nx);
    }
    bn_apply16<<<2048, BS, 0, stream>>>((const uint2*)r0_16, h16a,
                                        (const float*)d_in[9], (const float*)d_in[10], st1, 6);

    // ---- layer 1: 64 -> 128  (NPT=2: 3136 blocks) ----
    gather_agg_bf16<6><<<(N_NODES * 16 + BS - 1) / BS, BS, 0, stream>>>(h16a, rp, ssrc, (uint2*)AGG16);
    {
        const int nx = (N_NODES + 63) / 64;  // 782  (SLOTS*NPT = 32*2 = 64)
        gconv_lds<64, 128, 32, 2><<<xcd_grid(nx, 4), BS, 0, stream>>>(
            h16a, AGG16, (const float*)d_in[11], (const float*)d_in[12], (const float*)d_in[13],
            r1_16, st2, nx);
    }

    // ---- layer 2: 128 -> 64  (NPT=1: 3136 blocks) ----
    {
        const int nx = (N_NODES + 63) / 64;  // 782  (SLOTS*NPT = 64*1 = 64)
        prem_bn16<128, 64, 16, 1><<<xcd_grid(nx, 4), BS, 0, stream>>>(
            r1_16, (const float*)d_in[16], (const float*)d_in[17], (const float*)d_in[18],
            AGG16, q32, st2, (const float*)d_in[14], (const float*)d_in[15], nx);
    }
    gather_add_bf16<6, 1><<<512, BS, 0, stream>>>(AGG16, rp, ssrc, (float4*)q32, h2_16, st3);

    // ---- layer 3: 64 -> 32  (NPT=1: 1568 blocks) ----
    {
        const int nx = (N_NODES + 63) / 64;  // 782
        prem_bn16<64, 32, 16, 1><<<xcd_grid(nx, 2), BS, 0, stream>>>(
            h2_16, (const float*)d_in[21], (const float*)d_in[22], (const float*)d_in[23],
            AGG16, q32, st3, (const float*)d_in[19], (const float*)d_in[20], nx);
    }
    gather_add_bf16<5, 0><<<512, BS, 0, stream>>>(AGG16, rp, ssrc, (float4*)q32, (u16*)0, st4);

    // ---- fused BN(L3)+ReLU + output MLP ----
    outmlp_kernel<<<NB, BS, 0, stream>>>(
        q32, st4, (const float*)d_in[24], (const float*)d_in[25],
        out_W1, out_b1, out_W2, out_b2, (float*)d_out);
}

// Round 19
// 331.271 us; speedup vs baseline: 1.0606x; 1.0606x over previous
//
#include <hip/hip_runtime.h>

#define N_NODES 50000
#define N_EDGES 800000
#define BN_EPS 1e-5f

typedef unsigned int   u32;
typedef unsigned short u16;

__device__ __forceinline__ void fma4(float4& a, float s, const float4& w) {
    a.x += s * w.x; a.y += s * w.y; a.z += s * w.z; a.w += s * w.w;
}
__device__ __forceinline__ void add4(float4& a, const float4& b) {
    a.x += b.x; a.y += b.y; a.z += b.z; a.w += b.w;
}
// bf16 (RNE) pack/unpack
__device__ __forceinline__ u16 f2bf(float f) {
    union { u32 i; float f; } c; c.f = f;
    return (u16)((c.i + 0x7FFFu + ((c.i >> 16) & 1u)) >> 16);
}
__device__ __forceinline__ float4 bf4(uint2 w) {
    union { u32 i; float f; } a, b, c, d;
    a.i = w.x << 16; b.i = w.x & 0xFFFF0000u;
    c.i = w.y << 16; d.i = w.y & 0xFFFF0000u;
    return make_float4(a.f, b.f, c.f, d.f);
}
__device__ __forceinline__ uint2 pack4(const float4& v) {
    uint2 w;
    w.x = (u32)f2bf(v.x) | ((u32)f2bf(v.y) << 16);
    w.y = (u32)f2bf(v.z) | ((u32)f2bf(v.w) << 16);
    return w;
}
// extract element kk (compile-time) of 8 bf16 packed in a uint4
__device__ __forceinline__ float bfx(const uint4& v, int kk) {
    u32 w = ((const u32*)&v)[kk >> 1];
    union { u32 i; float f; } c;
    c.i = (kk & 1) ? (w & 0xFFFF0000u) : (w << 16);
    return c.f;
}

// XCD-aware 1-D grid decode (round-robin xcd = bid % 8).
template <int NY>
__device__ __forceinline__ bool xcd_decode(int nx, int& x, int& y) {
    const int s = blockIdx.x & (8 * NY - 1);
    const int g = blockIdx.x / (8 * NY);
    x = g * 8 + (s & 7);
    y = s >> 3;
    return x < nx;
}
static inline int xcd_grid(int nx, int ny) { return ((nx + 7) / 8 * 8) * ny; }

// ---------------------------------------------------------------------------
// zero cnt[] and the BN stats block (stats must be zero before hist_emb's emb)
__global__ void zero_all(int* __restrict__ cnt, float* __restrict__ stats) {
    int stride = gridDim.x * blockDim.x;
    for (int i = blockIdx.x * blockDim.x + threadIdx.x; i < N_NODES; i += stride)
        cnt[i] = 0;
    for (int i = blockIdx.x * blockDim.x + threadIdx.x; i < 5 * 256; i += stride)
        stats[i] = 0.f;
}

// ---------------------------------------------------------------------------
// MERGED: histogram of dst (blocks 0..1023)  ||  embedding Linear(5,32)+ReLU
// with fused BN stats, bf16 output (blocks 1024..1535). Independent work.
#define HIST_BLOCKS 1024
#define EMB_BLOCKS  512
__global__ __launch_bounds__(256) void hist_emb_kernel(
    const int* __restrict__ dst, int* __restrict__ cnt,
    const float* __restrict__ x, const float* __restrict__ W,
    const float* __restrict__ b, u16* __restrict__ out16,
    float* __restrict__ stats) {
    if (blockIdx.x < HIST_BLOCKS) {
        int i = blockIdx.x * 256 + threadIdx.x;
        int stride = HIST_BLOCKS * 256;
        for (; i < N_EDGES; i += stride) atomicAdd(&cnt[dst[i]], 1);
        return;
    }
    // ---- embedding part ----
    __shared__ float lsum[32], lssq[32];
    if (threadIdx.x < 32) { lsum[threadIdx.x] = 0.f; lssq[threadIdx.x] = 0.f; }
    __syncthreads();
    const int o = threadIdx.x & 31;
    const int total = N_NODES * 32;
    const int ebid = blockIdx.x - HIST_BLOCKS;
    float mys = 0.f, myq = 0.f;
    for (int base = ebid * 256; base < total; base += EMB_BLOCKS * 256) {
        int idx = base + threadIdx.x;
        float acc = 0.f;
        if (idx < total) {
            int n = idx >> 5;
            const float* xr = x + n * 5;
            acc = b[o];
#pragma unroll
            for (int k = 0; k < 5; ++k) acc += xr[k] * W[k * 32 + o];
            acc = fmaxf(acc, 0.f);
            out16[idx] = f2bf(acc);
        }
        mys += acc;
        myq += acc * acc;
    }
    mys += __shfl_xor(mys, 32);
    myq += __shfl_xor(myq, 32);
    if ((threadIdx.x & 63) < 32) { atomicAdd(&lsum[o], mys); atomicAdd(&lssq[o], myq); }
    __syncthreads();
    if (threadIdx.x < 32) {
        atomicAdd(&stats[threadIdx.x], lsum[threadIdx.x]);
        atomicAdd(&stats[32 + threadIdx.x], lssq[threadIdx.x]);
    }
}

// ---------------------------------------------------------------------------
// CSR scans
__global__ void scan1_kernel(const int* __restrict__ cnt, int* __restrict__ rp,
                             int* __restrict__ bsum) {
    __shared__ int s[256];
    int t = threadIdx.x;
    int idx = blockIdx.x * 256 + t;
    int v = (idx < N_NODES) ? cnt[idx] : 0;
    s[t] = v;
    __syncthreads();
    for (int off = 1; off < 256; off <<= 1) {
        int x = 0;
        if (t >= off) x = s[t - off];
        __syncthreads();
        s[t] += x;
        __syncthreads();
    }
    if (idx < N_NODES) rp[idx] = s[t] - v;
    if (t == 255) bsum[blockIdx.x] = s[255];
}
__global__ void scan2_kernel(int* __restrict__ bsum, int nb) {
    __shared__ int s[256];
    int t = threadIdx.x;
    int v = (t < nb) ? bsum[t] : 0;
    s[t] = v;
    __syncthreads();
    for (int off = 1; off < 256; off <<= 1) {
        int x = 0;
        if (t >= off) x = s[t - off];
        __syncthreads();
        s[t] += x;
        __syncthreads();
    }
    if (t < nb) bsum[t] = s[t] - v;
}
__global__ void scan3_kernel(int* __restrict__ rp, const int* __restrict__ bsum,
                             int* __restrict__ cnt) {
    int idx = blockIdx.x * 256 + threadIdx.x;
    if (idx < N_NODES) {
        rp[idx] += bsum[blockIdx.x];
        cnt[idx] = 0;
    }
    if (idx == 0) rp[N_NODES] = N_EDGES;
}
// after fill completes, cnt[n] == degree(n) again.
__global__ void fill_kernel(const int* __restrict__ src, const int* __restrict__ dst,
                            const int* __restrict__ rp, int* __restrict__ cur,
                            u16* __restrict__ ssrc) {
    int i = blockIdx.x * blockDim.x + threadIdx.x;
    int stride = gridDim.x * blockDim.x;
    for (; i < N_EDGES; i += stride) {
        int d = dst[i];
        int p = rp[d] + atomicAdd(&cur[d], 1);
        ssrc[p] = (u16)src[i];
    }
}

// ---------------------------------------------------------------------------
template <int D>
__device__ __forceinline__ void bn_finalize_lds(
    const float* __restrict__ stats, const float* __restrict__ g,
    const float* __restrict__ beta, float* sc, float* sh) {
    const float invN = 1.f / (float)N_NODES;
    for (int f = threadIdx.x; f < D; f += 256) {
        float m = stats[f] * invN;
        float var = stats[D + f] * invN - m * m;
        float a = g[f] * rsqrtf(var + BN_EPS);
        sc[f] = a;
        sh[f] = beta[f] - m * a;
    }
    __syncthreads();
}

// ---------------------------------------------------------------------------
// batchnorm + relu: read bf16 raw, write bf16 normalized mirror.
__global__ __launch_bounds__(256) void bn_apply16(
    const uint2* __restrict__ in16, u16* __restrict__ out16,
    const float* __restrict__ g, const float* __restrict__ beta,
    const float* __restrict__ stats, int logD) {
    const int D = 1 << logD;
    const int total4 = N_NODES << (logD - 2);
    const float invN = 1.f / (float)N_NODES;
    int idx = blockIdx.x * blockDim.x + threadIdx.x;
    int stride = gridDim.x * blockDim.x;
    for (; idx < total4; idx += stride) {
        int f = (idx & ((D >> 2) - 1)) << 2;
        float4 v = bf4(in16[idx]);
        float* vp = (float*)&v;
#pragma unroll
        for (int c = 0; c < 4; ++c) {
            float m = stats[f + c] * invN;
            float var = stats[D + f + c] * invN - m * m;
            vp[c] = fmaxf((vp[c] - m) * rsqrtf(var + BN_EPS) * g[f + c] + beta[f + c], 0.f);
        }
        ((uint2*)out16)[idx] = pack4(v);
    }
}

// ---------------------------------------------------------------------------
// agg16[n] = bf16( sum over CSR row of bf16 h16[ssrc[e]] )
template <int LOGD>
__global__ __launch_bounds__(256) void gather_agg_bf16(
    const u16* __restrict__ h16, const int* __restrict__ rp,
    const u16* __restrict__ ssrc, uint2* __restrict__ agg16) {
    constexpr int QSH = LOGD - 2;
    int tid = blockIdx.x * 256 + threadIdx.x;
    int node = tid >> QSH;
    if (node >= N_NODES) return;
    int q = tid & ((1 << QSH) - 1);
    int e0 = rp[node], e1 = rp[node + 1];
    float4 acc = make_float4(0.f, 0.f, 0.f, 0.f);
    int e = e0;
    for (; e + 4 <= e1; e += 4) {
        int s0 = ssrc[e], s1 = ssrc[e + 1], s2 = ssrc[e + 2], s3 = ssrc[e + 3];
        uint2 w0 = ((const uint2*)(h16 + ((size_t)s0 << LOGD)))[q];
        uint2 w1 = ((const uint2*)(h16 + ((size_t)s1 << LOGD)))[q];
        uint2 w2 = ((const uint2*)(h16 + ((size_t)s2 << LOGD)))[q];
        uint2 w3 = ((const uint2*)(h16 + ((size_t)s3 << LOGD)))[q];
        float4 v0 = bf4(w0), v1 = bf4(w1), v2 = bf4(w2), v3 = bf4(w3);
        add4(v0, v1); add4(v2, v3); add4(acc, v0); add4(acc, v2);
    }
    for (; e < e1; ++e) {
        float4 v = bf4(((const uint2*)(h16 + ((size_t)ssrc[e] << LOGD)))[q]);
        add4(acc, v);
    }
    agg16[tid] = pack4(acc);
}

// ---------------------------------------------------------------------------
// Layer-0 dual matmul, bf16 operands; BN folded per-node via linearity.
// Output bf16 raw. XCD-aware (NY=2).
template <int DIN, int DOUT, int OBL, int NPT>
__global__ __launch_bounds__(256) void gconv_bn0(
    const u16* __restrict__ h16, const u16* __restrict__ agg16,
    const float* __restrict__ Wrel, const float* __restrict__ brel,
    const float* __restrict__ Wroot, u16* __restrict__ out16,
    const float* __restrict__ stats_in, const float* __restrict__ g_in,
    const float* __restrict__ beta_in, const int* __restrict__ deg,
    float* __restrict__ stats_out, int nx) {
    constexpr int NY = 2;
    constexpr int LPN = OBL / 4;
    constexpr int SLOTS = 256 / LPN;
    constexpr int KS = 8;
    constexpr int TOT4 = DIN * OBL / 4;
    int bx, by;
    if (!xcd_decode<NY>(nx, bx, by)) return;
    __shared__ __align__(16) float wl[2 * DIN * OBL];
    __shared__ __align__(16) float sc[DIN];
    __shared__ __align__(16) float sh[DIN];
    __shared__ float lsum[OBL], lssq[OBL];
    const int ob0 = by * OBL;
    for (int e4 = threadIdx.x; e4 < TOT4; e4 += 256) {
        int k = e4 / (OBL / 4);
        int j = (e4 % (OBL / 4)) * 4;
        ((float4*)wl)[e4] = *(const float4*)(Wrel + (size_t)k * DOUT + ob0 + j);
        ((float4*)wl)[TOT4 + e4] = *(const float4*)(Wroot + (size_t)k * DOUT + ob0 + j);
    }
    if (threadIdx.x < OBL) { lsum[threadIdx.x] = 0.f; lssq[threadIdx.x] = 0.f; }
    bn_finalize_lds<DIN>(stats_in, g_in, beta_in, sc, sh);  // syncs

    const int q = threadIdx.x & (LPN - 1);
    const int slot = threadIdx.x / LPN;
    const int o0 = ob0 + q * 4;
    const int nbase = bx * (SLOTS * NPT) + slot;

    float degf[NPT];
#pragma unroll
    for (int i = 0; i < NPT; ++i) {
        int n = nbase + i * SLOTS;
        degf[i] = (n < N_NODES) ? (float)deg[n] : 0.f;
    }

    float4 bias = *(const float4*)(brel + o0);
    float4 acc[NPT];
#pragma unroll
    for (int i = 0; i < NPT; ++i) acc[i] = bias;

#pragma unroll 1
    for (int s = 0; s < DIN / KS; ++s) {
        const int k0 = s * KS;
        float4 s2[2] = {((const float4*)sc)[k0 / 4], ((const float4*)sc)[k0 / 4 + 1]};
        float4 t2[2] = {((const float4*)sh)[k0 / 4], ((const float4*)sh)[k0 / 4 + 1]};
        const float* scp = (const float*)s2;
        const float* shp = (const float*)t2;
        uint4 hv16[NPT], av16[NPT];
#pragma unroll
        for (int i = 0; i < NPT; ++i) {
            int n = nbase + i * SLOTS;
            int nn = (n < N_NODES) ? n : 0;
            hv16[i] = *(const uint4*)(h16 + (size_t)nn * DIN + k0);
            av16[i] = *(const uint4*)(agg16 + (size_t)nn * DIN + k0);
        }
#pragma unroll
        for (int kk = 0; kk < KS; ++kk) {
            float4 wr = *(const float4*)&wl[(k0 + kk) * OBL + q * 4];
            float4 wo = *(const float4*)&wl[DIN * OBL + (k0 + kk) * OBL + q * 4];
#pragma unroll
            for (int i = 0; i < NPT; ++i) {
                float a  = fmaf(bfx(av16[i], kk), scp[kk], degf[i] * shp[kk]);
                float hh = fmaf(bfx(hv16[i], kk), scp[kk], shp[kk]);
                fma4(acc[i], a, wr);
                fma4(acc[i], hh, wo);
            }
        }
    }
#pragma unroll
    for (int i = 0; i < NPT; ++i) {
        int n = nbase + i * SLOTS;
        if (n < N_NODES)
            *(uint2*)(out16 + (size_t)n * DOUT + o0) = pack4(acc[i]);
        else
            acc[i] = make_float4(0.f, 0.f, 0.f, 0.f);
    }
    float4 s4 = make_float4(0.f, 0.f, 0.f, 0.f);
    float4 q4 = make_float4(0.f, 0.f, 0.f, 0.f);
#pragma unroll
    for (int i = 0; i < NPT; ++i) {
        s4.x += acc[i].x; s4.y += acc[i].y; s4.z += acc[i].z; s4.w += acc[i].w;
        q4.x += acc[i].x * acc[i].x; q4.y += acc[i].y * acc[i].y;
        q4.z += acc[i].z * acc[i].z; q4.w += acc[i].w * acc[i].w;
    }
#pragma unroll
    for (int d = LPN; d < 64; d <<= 1) {
        s4.x += __shfl_xor(s4.x, d); s4.y += __shfl_xor(s4.y, d);
        s4.z += __shfl_xor(s4.z, d); s4.w += __shfl_xor(s4.w, d);
        q4.x += __shfl_xor(q4.x, d); q4.y += __shfl_xor(q4.y, d);
        q4.z += __shfl_xor(q4.z, d); q4.w += __shfl_xor(q4.w, d);
    }
    if ((threadIdx.x & 63) < LPN) {
        int c = q * 4;
        atomicAdd(&lsum[c + 0], s4.x); atomicAdd(&lsum[c + 1], s4.y);
        atomicAdd(&lsum[c + 2], s4.z); atomicAdd(&lsum[c + 3], s4.w);
        atomicAdd(&lssq[c + 0], q4.x); atomicAdd(&lssq[c + 1], q4.y);
        atomicAdd(&lssq[c + 2], q4.z); atomicAdd(&lssq[c + 3], q4.w);
    }
    __syncthreads();
    if (threadIdx.x < OBL) {
        atomicAdd(&stats_out[ob0 + threadIdx.x], lsum[threadIdx.x]);
        atomicAdd(&stats_out[DOUT + ob0 + threadIdx.x], lssq[threadIdx.x]);
    }
}

// ---------------------------------------------------------------------------
// dual matmul, bf16 operands -> bf16 raw output + stats; XCD-aware (NY=4).
template <int DIN, int DOUT, int OBL, int NPT>
__global__ __launch_bounds__(256) void gconv_lds(
    const u16* __restrict__ h16, const u16* __restrict__ agg16,
    const float* __restrict__ Wrel, const float* __restrict__ brel,
    const float* __restrict__ Wroot, u16* __restrict__ out16,
    float* __restrict__ stats_out, int nx) {
    constexpr int NY = DOUT / OBL;
    constexpr int LPN = OBL / 4;
    constexpr int SLOTS = 256 / LPN;
    constexpr int KS = 8;
    constexpr int TOT4 = DIN * OBL / 4;
    int bx, by;
    if (!xcd_decode<NY>(nx, bx, by)) return;
    __shared__ __align__(16) float wl[2 * DIN * OBL];
    __shared__ float lsum[OBL], lssq[OBL];
    const int ob0 = by * OBL;
    for (int e4 = threadIdx.x; e4 < TOT4; e4 += 256) {
        int k = e4 / (OBL / 4);
        int j = (e4 % (OBL / 4)) * 4;
        ((float4*)wl)[e4] = *(const float4*)(Wrel + (size_t)k * DOUT + ob0 + j);
        ((float4*)wl)[TOT4 + e4] = *(const float4*)(Wroot + (size_t)k * DOUT + ob0 + j);
    }
    if (threadIdx.x < OBL) { lsum[threadIdx.x] = 0.f; lssq[threadIdx.x] = 0.f; }
    __syncthreads();

    const int q = threadIdx.x & (LPN - 1);
    const int slot = threadIdx.x / LPN;
    const int o0 = ob0 + q * 4;
    const int nbase = bx * (SLOTS * NPT) + slot;

    float4 bias = *(const float4*)(brel + o0);
    float4 acc[NPT];
#pragma unroll
    for (int i = 0; i < NPT; ++i) acc[i] = bias;

#pragma unroll 1
    for (int s = 0; s < DIN / KS; ++s) {
        const int k0 = s * KS;
        uint4 hv16[NPT], av16[NPT];
#pragma unroll
        for (int i = 0; i < NPT; ++i) {
            int n = nbase + i * SLOTS;
            int nn = (n < N_NODES) ? n : 0;
            hv16[i] = *(const uint4*)(h16 + (size_t)nn * DIN + k0);
            av16[i] = *(const uint4*)(agg16 + (size_t)nn * DIN + k0);
        }
#pragma unroll
        for (int kk = 0; kk < KS; ++kk) {
            float4 wr = *(const float4*)&wl[(k0 + kk) * OBL + q * 4];
            float4 wo = *(const float4*)&wl[DIN * OBL + (k0 + kk) * OBL + q * 4];
#pragma unroll
            for (int i = 0; i < NPT; ++i) {
                fma4(acc[i], bfx(av16[i], kk), wr);
                fma4(acc[i], bfx(hv16[i], kk), wo);
            }
        }
    }
#pragma unroll
    for (int i = 0; i < NPT; ++i) {
        int n = nbase + i * SLOTS;
        if (n < N_NODES)
            *(uint2*)(out16 + (size_t)n * DOUT + o0) = pack4(acc[i]);
        else
            acc[i] = make_float4(0.f, 0.f, 0.f, 0.f);
    }
    float4 s4 = make_float4(0.f, 0.f, 0.f, 0.f);
    float4 q4 = make_float4(0.f, 0.f, 0.f, 0.f);
#pragma unroll
    for (int i = 0; i < NPT; ++i) {
        s4.x += acc[i].x; s4.y += acc[i].y; s4.z += acc[i].z; s4.w += acc[i].w;
        q4.x += acc[i].x * acc[i].x; q4.y += acc[i].y * acc[i].y;
        q4.z += acc[i].z * acc[i].z; q4.w += acc[i].w * acc[i].w;
    }
#pragma unroll
    for (int d = LPN; d < 64; d <<= 1) {
        s4.x += __shfl_xor(s4.x, d); s4.y += __shfl_xor(s4.y, d);
        s4.z += __shfl_xor(s4.z, d); s4.w += __shfl_xor(s4.w, d);
        q4.x += __shfl_xor(q4.x, d); q4.y += __shfl_xor(q4.y, d);
        q4.z += __shfl_xor(q4.z, d); q4.w += __shfl_xor(q4.w, d);
    }
    if ((threadIdx.x & 63) < LPN) {
        int c = q * 4;
        atomicAdd(&lsum[c + 0], s4.x); atomicAdd(&lsum[c + 1], s4.y);
        atomicAdd(&lsum[c + 2], s4.z); atomicAdd(&lsum[c + 3], s4.w);
        atomicAdd(&lssq[c + 0], q4.x); atomicAdd(&lssq[c + 1], q4.y);
        atomicAdd(&lssq[c + 2], q4.z); atomicAdd(&lssq[c + 3], q4.w);
    }
    __syncthreads();
    if (threadIdx.x < OBL) {
        atomicAdd(&stats_out[ob0 + threadIdx.x], lsum[threadIdx.x]);
        atomicAdd(&stats_out[DOUT + ob0 + threadIdx.x], lssq[threadIdx.x]);
    }
}

// ---------------------------------------------------------------------------
// P(bf16) = bnrelu(h16)@Wrel ; Q(fp32) = bnrelu(h16)@Wroot + brel
template <int DIN, int DOUT, int OBL, int NPT>
__global__ __launch_bounds__(256) void prem_bn16(
    const u16* __restrict__ h16, const float* __restrict__ Wrel,
    const float* __restrict__ brel, const float* __restrict__ Wroot,
    u16* __restrict__ P16, float* __restrict__ Q,
    const float* __restrict__ stats_in, const float* __restrict__ g_in,
    const float* __restrict__ beta_in, int nx) {
    constexpr int NY = DOUT / OBL;
    constexpr int LPN = OBL / 4;
    constexpr int SLOTS = 256 / LPN;
    constexpr int KS = 8;
    constexpr int TOT4 = DIN * OBL / 4;
    int bx, by;
    if (!xcd_decode<NY>(nx, bx, by)) return;
    __shared__ __align__(16) float wl[2 * DIN * OBL];
    __shared__ __align__(16) float sc[DIN];
    __shared__ __align__(16) float sh[DIN];
    const int ob0 = by * OBL;
    for (int e4 = threadIdx.x; e4 < TOT4; e4 += 256) {
        int k = e4 / (OBL / 4);
        int j = (e4 % (OBL / 4)) * 4;
        ((float4*)wl)[e4] = *(const float4*)(Wrel + (size_t)k * DOUT + ob0 + j);
        ((float4*)wl)[TOT4 + e4] = *(const float4*)(Wroot + (size_t)k * DOUT + ob0 + j);
    }
    bn_finalize_lds<DIN>(stats_in, g_in, beta_in, sc, sh);  // syncs

    const int q = threadIdx.x & (LPN - 1);
    const int slot = threadIdx.x / LPN;
    const int o0 = ob0 + q * 4;
    const int nbase = bx * (SLOTS * NPT) + slot;

    float4 bias = *(const float4*)(brel + o0);
    float4 accp[NPT], accq[NPT];
#pragma unroll
    for (int i = 0; i < NPT; ++i) {
        accp[i] = make_float4(0.f, 0.f, 0.f, 0.f);
        accq[i] = bias;
    }

#pragma unroll 1
    for (int s = 0; s < DIN / KS; ++s) {
        const int k0 = s * KS;
        float4 s2[2] = {((const float4*)sc)[k0 / 4], ((const float4*)sc)[k0 / 4 + 1]};
        float4 t2[2] = {((const float4*)sh)[k0 / 4], ((const float4*)sh)[k0 / 4 + 1]};
        const float* scp = (const float*)s2;
        const float* shp = (const float*)t2;
        uint4 hv16[NPT];
#pragma unroll
        for (int i = 0; i < NPT; ++i) {
            int n = nbase + i * SLOTS;
            int nn = (n < N_NODES) ? n : 0;
            hv16[i] = *(const uint4*)(h16 + (size_t)nn * DIN + k0);
        }
#pragma unroll
        for (int kk = 0; kk < KS; ++kk) {
            float4 wr = *(const float4*)&wl[(k0 + kk) * OBL + q * 4];
            float4 wo = *(const float4*)&wl[DIN * OBL + (k0 + kk) * OBL + q * 4];
#pragma unroll
            for (int i = 0; i < NPT; ++i) {
                float hh = fmaxf(fmaf(bfx(hv16[i], kk), scp[kk], shp[kk]), 0.f);
                fma4(accp[i], hh, wr);
                fma4(accq[i], hh, wo);
            }
        }
    }
#pragma unroll
    for (int i = 0; i < NPT; ++i) {
        int n = nbase + i * SLOTS;
        if (n < N_NODES) {
            *(uint2*)(P16 + (size_t)n * DOUT + o0) = pack4(accp[i]);
            *(float4*)(Q + (size_t)n * DOUT + o0) = accq[i];
        }
    }
}

// ---------------------------------------------------------------------------
// out = Q_preloaded + sum over CSR row of bf16 P16[ssrc[e]]; fused BN stats.
template <int LOGD, int W16>
__global__ __launch_bounds__(256) void gather_add_bf16(
    const u16* __restrict__ P16, const int* __restrict__ rp,
    const u16* __restrict__ ssrc, float4* __restrict__ qio,
    u16* __restrict__ out16, float* __restrict__ stats) {
    constexpr int D = 1 << LOGD;
    constexpr int Q4 = D / 4;
    __shared__ float lsum[D], lssq[D];
    if (threadIdx.x < D) { lsum[threadIdx.x] = 0.f; lssq[threadIdx.x] = 0.f; }
    __syncthreads();

    const int total = N_NODES * Q4;
    const int q = threadIdx.x & (Q4 - 1);
    float4 mys = make_float4(0.f, 0.f, 0.f, 0.f);
    float4 myq = make_float4(0.f, 0.f, 0.f, 0.f);

    for (int base = blockIdx.x * 256; base < total; base += gridDim.x * 256) {
        int tid = base + threadIdx.x;
        float4 acc = make_float4(0.f, 0.f, 0.f, 0.f);
        if (tid < total) {
            int node = tid >> (LOGD - 2);
            int e0 = rp[node], e1 = rp[node + 1];
            acc = qio[tid];
            int e = e0;
            for (; e + 4 <= e1; e += 4) {
                int s0 = ssrc[e], s1 = ssrc[e + 1], s2 = ssrc[e + 2], s3 = ssrc[e + 3];
                uint2 w0 = ((const uint2*)(P16 + ((size_t)s0 << LOGD)))[q];
                uint2 w1 = ((const uint2*)(P16 + ((size_t)s1 << LOGD)))[q];
                uint2 w2 = ((const uint2*)(P16 + ((size_t)s2 << LOGD)))[q];
                uint2 w3 = ((const uint2*)(P16 + ((size_t)s3 << LOGD)))[q];
                float4 v0 = bf4(w0), v1 = bf4(w1), v2 = bf4(w2), v3 = bf4(w3);
                add4(v0, v1); add4(v2, v3); add4(acc, v0); add4(acc, v2);
            }
            for (; e < e1; ++e) {
                float4 v = bf4(((const uint2*)(P16 + ((size_t)ssrc[e] << LOGD)))[q]);
                add4(acc, v);
            }
            if (W16)
                ((uint2*)out16)[tid] = pack4(acc);
            else
                qio[tid] = acc;
        }
        mys.x += acc.x; mys.y += acc.y; mys.z += acc.z; mys.w += acc.w;
        myq.x += acc.x * acc.x; myq.y += acc.y * acc.y;
        myq.z += acc.z * acc.z; myq.w += acc.w * acc.w;
    }
#pragma unroll
    for (int d = Q4; d < 64; d <<= 1) {
        mys.x += __shfl_xor(mys.x, d); mys.y += __shfl_xor(mys.y, d);
        mys.z += __shfl_xor(mys.z, d); mys.w += __shfl_xor(mys.w, d);
        myq.x += __shfl_xor(myq.x, d); myq.y += __shfl_xor(myq.y, d);
        myq.z += __shfl_xor(myq.z, d); myq.w += __shfl_xor(myq.w, d);
    }
    if ((threadIdx.x & 63) < Q4) {
        atomicAdd(&lsum[4 * q + 0], mys.x); atomicAdd(&lsum[4 * q + 1], mys.y);
        atomicAdd(&lsum[4 * q + 2], mys.z); atomicAdd(&lsum[4 * q + 3], mys.w);
        atomicAdd(&lssq[4 * q + 0], myq.x); atomicAdd(&lssq[4 * q + 1], myq.y);
        atomicAdd(&lssq[4 * q + 2], myq.z); atomicAdd(&lssq[4 * q + 3], myq.w);
    }
    __syncthreads();
    if (threadIdx.x < D) {
        atomicAdd(&stats[threadIdx.x], lsum[threadIdx.x]);
        atomicAdd(&stats[D + threadIdx.x], lssq[threadIdx.x]);
    }
}

// ---------------------------------------------------------------------------
// fused: BN(layer3)+ReLU -> Linear(32,16)+ReLU -> Linear(16,2)
__global__ __launch_bounds__(256) void outmlp_kernel(
    const float* __restrict__ h, const float* __restrict__ stats,
    const float* __restrict__ g, const float* __restrict__ beta,
    const float* __restrict__ W1, const float* __restrict__ b1,
    const float* __restrict__ W2, const float* __restrict__ b2,
    float* __restrict__ out) {
    int n = blockIdx.x * 256 + threadIdx.x;
    if (n >= N_NODES) return;
    const float invN = 1.f / (float)N_NODES;
    const float4* hr4 = (const float4*)(h + (size_t)n * 32);
    float hv[32];
#pragma unroll
    for (int k4 = 0; k4 < 8; ++k4) {
        float4 v = hr4[k4];
        float* vp = (float*)&v;
#pragma unroll
        for (int c = 0; c < 4; ++c) {
            int f = 4 * k4 + c;
            float m = stats[f] * invN;
            float var = stats[32 + f] * invN - m * m;
            hv[f] = fmaxf((vp[c] - m) * rsqrtf(var + BN_EPS) * g[f] + beta[f], 0.f);
        }
    }
    float hid[16];
#pragma unroll
    for (int j = 0; j < 16; ++j) hid[j] = b1[j];
#pragma unroll
    for (int k = 0; k < 32; ++k) {
        float hk = hv[k];
#pragma unroll
        for (int j = 0; j < 16; ++j) hid[j] += hk * W1[k * 16 + j];
    }
    float o0 = b2[0], o1 = b2[1];
#pragma unroll
    for (int j = 0; j < 16; ++j) {
        float t = fmaxf(hid[j], 0.f);
        o0 += t * W2[j * 2 + 0];
        o1 += t * W2[j * 2 + 1];
    }
    out[n * 2 + 0] = o0;
    out[n * 2 + 1] = o1;
}

// ---------------------------------------------------------------------------
extern "C" void kernel_launch(void* const* d_in, const int* in_sizes, int n_in,
                              void* d_out, int out_size, void* d_ws, size_t ws_size,
                              hipStream_t stream) {
    const float* x        = (const float*)d_in[0];
    const int*   ei       = (const int*)d_in[1];
    const int*   src      = ei;
    const int*   dst      = ei + N_EDGES;
    const float* emb_W    = (const float*)d_in[2];
    const float* emb_b    = (const float*)d_in[3];
    const float* emb_g    = (const float*)d_in[4];
    const float* emb_beta = (const float*)d_in[5];
    const float* out_W1   = (const float*)d_in[26];
    const float* out_b1   = (const float*)d_in[27];
    const float* out_W2   = (const float*)d_in[28];
    const float* out_b2   = (const float*)d_in[29];

    float* ws = (float*)d_ws;
    // fp32 regions
    float* q32   = ws;                                   // N x 64 fp32 (Q panels; final h)
    float* stats = ws + (size_t)N_NODES * 64;            // 5 x 256
    // bf16 regions (u16 counts)
    u16* h16emb = (u16*)(stats + 5 * 256);               // N x 32
    u16* AGG16  = h16emb + (size_t)N_NODES * 32;         // N x 64 (agg / P panels)
    u16* r0_16  = AGG16 + (size_t)N_NODES * 64;          // N x 64 raw L0 out
    u16* h16a   = r0_16 + (size_t)N_NODES * 64;          // N x 64 normalized L0
    u16* r1_16  = h16a + (size_t)N_NODES * 64;           // N x 128 raw L1 out
    u16* h2_16  = r1_16 + (size_t)N_NODES * 128;         // N x 64 raw L2 out
    int* rp     = (int*)(h2_16 + (size_t)N_NODES * 64);  // 50001
    int* cnt    = rp + N_NODES + 1;
    int* bsum   = cnt + N_NODES;
    u16* ssrc   = (u16*)(bsum + 256);                    // 800000

    float* st0 = stats;        // emb BN (D=32)
    float* st1 = stats + 256;  // L0 (D=64)
    float* st2 = stats + 512;  // L1 (D=128)
    float* st3 = stats + 768;  // L2 (D=64)
    float* st4 = stats + 1024; // L3 (D=32)

    const int BS = 256;
    const int NB = (N_NODES + BS - 1) / BS;  // 196

    // ---- zero cnt + stats, then merged hist||emb ----
    zero_all<<<64, BS, 0, stream>>>(cnt, stats);
    hist_emb_kernel<<<HIST_BLOCKS + EMB_BLOCKS, BS, 0, stream>>>(
        dst, cnt, x, emb_W, emb_b, h16emb, st0);

    // ---- CSR scans + fill ----
    scan1_kernel<<<NB, 256, 0, stream>>>(cnt, rp, bsum);
    scan2_kernel<<<1, 256, 0, stream>>>(bsum, NB);
    scan3_kernel<<<NB, 256, 0, stream>>>(rp, bsum, cnt);
    fill_kernel<<<1024, BS, 0, stream>>>(src, dst, rp, cnt, ssrc);
    // after fill: cnt[n] == degree(n)

    // ---- layer 0: 32 -> 64  (NPT=4, best-found) ----
    gather_agg_bf16<5><<<(N_NODES * 8 + BS - 1) / BS, BS, 0, stream>>>(h16emb, rp, ssrc, (uint2*)AGG16);
    {
        const int nx = (N_NODES + 127) / 128;  // 391  (SLOTS*NPT = 32*4 = 128)
        gconv_bn0<32, 64, 32, 4><<<xcd_grid(nx, 2), BS, 0, stream>>>(
            h16emb, AGG16, (const float*)d_in[6], (const float*)d_in[7], (const float*)d_in[8],
            r0_16, st0, emb_g, emb_beta, cnt, st1, nx);
    }
    bn_apply16<<<2048, BS, 0, stream>>>((const uint2*)r0_16, h16a,
                                        (const float*)d_in[9], (const float*)d_in[10], st1, 6);

    // ---- layer 1: 64 -> 128  (NPT=4, best-found) ----
    gather_agg_bf16<6><<<(N_NODES * 16 + BS - 1) / BS, BS, 0, stream>>>(h16a, rp, ssrc, (uint2*)AGG16);
    {
        const int nx = (N_NODES + 127) / 128;  // 391
        gconv_lds<64, 128, 32, 4><<<xcd_grid(nx, 4), BS, 0, stream>>>(
            h16a, AGG16, (const float*)d_in[11], (const float*)d_in[12], (const float*)d_in[13],
            r1_16, st2, nx);
    }

    // ---- layer 2: 128 -> 64  (NPT=2, best-found) ----
    {
        const int nx = (N_NODES + 127) / 128;  // 391  (SLOTS*NPT = 64*2 = 128)
        prem_bn16<128, 64, 16, 2><<<xcd_grid(nx, 4), BS, 0, stream>>>(
            r1_16, (const float*)d_in[16], (const float*)d_in[17], (const float*)d_in[18],
            AGG16, q32, st2, (const float*)d_in[14], (const float*)d_in[15], nx);
    }
    gather_add_bf16<6, 1><<<512, BS, 0, stream>>>(AGG16, rp, ssrc, (float4*)q32, h2_16, st3);

    // ---- layer 3: 64 -> 32  (NPT=2, best-found) ----
    {
        const int nx = (N_NODES + 127) / 128;  // 391
        prem_bn16<64, 32, 16, 2><<<xcd_grid(nx, 2), BS, 0, stream>>>(
            h2_16, (const float*)d_in[21], (const float*)d_in[22], (const float*)d_in[23],
            AGG16, q32, st3, (const float*)d_in[19], (const float*)d_in[20], nx);
    }
    gather_add_bf16<5, 0><<<512, BS, 0, stream>>>(AGG16, rp, ssrc, (float4*)q32, (u16*)0, st4);

    // ---- fused BN(L3)+ReLU + output MLP ----
    outmlp_kernel<<<NB, BS, 0, stream>>>(
        q32, st4, (const float*)d_in[24], (const float*)d_in[25],
        out_W1, out_b1, out_W2, out_b2, (float*)d_out);
}